// Round 4
// baseline (2442.275 us; speedup 1.0000x reference)
//
#include <hip/hip_runtime.h>
#include <hip/hip_bf16.h>
#include <math.h>

// Problem dims
#define VOCAB 50001
#define EDIM 256
#define HDIM 256          // per-direction hidden
#define GDIM 1024         // 4*HDIM gates
#define KTAG 9
#define NB 64             // batch
#define NT 256            // time

// workspace layout (float offsets)
static constexpr size_t XP_OFF    = 0;                          // xproj [16384][2048]
static constexpr size_t HX_OFF    = XP_OFF + (size_t)16384*2048;// h exchange [2][256][128]
static constexpr size_t FLAGS_OFF = HX_OFF + 65536;             // 256 ints (pad 512)
static constexpr size_t BIAS_OFF  = FLAGS_OFF + 512;            // [2048]
static constexpr size_t HS_OFF    = BIAS_OFF + 2048;            // hstore [16384][512]
static constexpr size_t EM_OFF    = HS_OFF + (size_t)16384*512; // emissions [16384][9]

// readlane: h is wave-uniform -> SGPR operand for fma
#define RL(v, l) __int_as_float(__builtin_amdgcn_readlane(__float_as_int(v), (l)))

// ---------------------------------------------------------------------------
__global__ __launch_bounds__(256) void k_prep(const float* __restrict__ bif,
                                              const float* __restrict__ bhf,
                                              const float* __restrict__ bib,
                                              const float* __restrict__ bhb,
                                              float* __restrict__ ws) {
    int t = blockIdx.x * 256 + threadIdx.x;   // grid 16x256 = 4096
    float* bias = ws + BIAS_OFF;
    if (t < 2048) {
        int d = t >> 10, g = t & 1023;
        bias[t] = d ? (bib[g] + bhb[g]) : (bif[g] + bhf[g]);
    }
    int* flags = (int*)(ws + FLAGS_OFF);
    if (t < 256) flags[t] = 0;
}

// ---------------------------------------------------------------------------
// xproj GEMM: M=16384 rows (r = t*64+b, A row = embed[x[b,t]]), N=2048
// (w_ih_f rows 0..1023 | w_ih_b rows 1024..2047), K=256. fp32, 64x64 tiles.
#define BKC 32
__global__ __launch_bounds__(256) void k_xproj(const int* __restrict__ x,
                                               const float* __restrict__ embed,
                                               const float* __restrict__ wih_f,
                                               const float* __restrict__ wih_b,
                                               float* __restrict__ ws) {
    float* xp = ws + XP_OFF;
    const float* bias = ws + BIAS_OFF;
    __shared__ float As[BKC][68];
    __shared__ float Bs[BKC][68];
    __shared__ int ids[64];
    const int bm = blockIdx.x;      // 0..255
    const int bn = blockIdx.y;      // 0..31
    const int tid = threadIdx.x;
    const int tx = tid & 15, ty = tid >> 4;

    if (tid < 64) {
        int r = bm * 64 + tid;
        int t = r >> 6, b = r & 63;
        ids[tid] = x[b * 256 + t];
    }
    __syncthreads();

    float acc[4][4];
#pragma unroll
    for (int i = 0; i < 4; ++i)
#pragma unroll
        for (int j = 0; j < 4; ++j) acc[i][j] = 0.f;

    const int lm = tid >> 2;
    const int lks = (tid & 3) * 8;

    for (int k0 = 0; k0 < 256; k0 += BKC) {
        {
            const float* src = embed + (size_t)ids[lm] * 256 + k0 + lks;
            float4 a0 = *reinterpret_cast<const float4*>(src);
            float4 a1 = *reinterpret_cast<const float4*>(src + 4);
            As[lks + 0][lm] = a0.x; As[lks + 1][lm] = a0.y;
            As[lks + 2][lm] = a0.z; As[lks + 3][lm] = a0.w;
            As[lks + 4][lm] = a1.x; As[lks + 5][lm] = a1.y;
            As[lks + 6][lm] = a1.z; As[lks + 7][lm] = a1.w;
        }
        {
            int gn = bn * 64 + lm;
            const float* wsrc = (gn < 1024) ? (wih_f + (size_t)gn * 256)
                                            : (wih_b + (size_t)(gn - 1024) * 256);
            const float* src = wsrc + k0 + lks;
            float4 b0 = *reinterpret_cast<const float4*>(src);
            float4 b1 = *reinterpret_cast<const float4*>(src + 4);
            Bs[lks + 0][lm] = b0.x; Bs[lks + 1][lm] = b0.y;
            Bs[lks + 2][lm] = b0.z; Bs[lks + 3][lm] = b0.w;
            Bs[lks + 4][lm] = b1.x; Bs[lks + 5][lm] = b1.y;
            Bs[lks + 6][lm] = b1.z; Bs[lks + 7][lm] = b1.w;
        }
        __syncthreads();
#pragma unroll
        for (int k = 0; k < BKC; ++k) {
            float4 a = *reinterpret_cast<const float4*>(&As[k][ty * 4]);
            float4 bq = *reinterpret_cast<const float4*>(&Bs[k][tx * 4]);
            acc[0][0] += a.x * bq.x; acc[0][1] += a.x * bq.y; acc[0][2] += a.x * bq.z; acc[0][3] += a.x * bq.w;
            acc[1][0] += a.y * bq.x; acc[1][1] += a.y * bq.y; acc[1][2] += a.y * bq.z; acc[1][3] += a.y * bq.w;
            acc[2][0] += a.z * bq.x; acc[2][1] += a.z * bq.y; acc[2][2] += a.z * bq.z; acc[2][3] += a.z * bq.w;
            acc[3][0] += a.w * bq.x; acc[3][1] += a.w * bq.y; acc[3][2] += a.w * bq.z; acc[3][3] += a.w * bq.w;
        }
        __syncthreads();
    }

    const int gm = bm * 64 + ty * 4;
    const int gn = bn * 64 + tx * 4;
#pragma unroll
    for (int i = 0; i < 4; ++i) {
        float4 o;
        o.x = acc[i][0] + bias[gn + 0];
        o.y = acc[i][1] + bias[gn + 1];
        o.z = acc[i][2] + bias[gn + 2];
        o.w = acc[i][3] + bias[gn + 3];
        *reinterpret_cast<float4*>(xp + (size_t)(gm + i) * 2048 + gn) = o;
    }
}

// ---------------------------------------------------------------------------
// Recurrence v2.1: weights fully CU-resident, spill-free.
// 256 blocks = (half, dir, batch); 512 threads = gate-rows of the block's
// j-half. Row k-split: k[0,180) in VGPRs (45 float4 = 180 regs), k[180,256)
// in LDS (19 float4/row). amdgpu_waves_per_eu(2,2) pins 2 waves/EU ->
// 256-VGPR budget so w4[] stays in registers (round-3 spill fix).
#define WREGS 45
#define WLDSC 19
#define REC_LDS_FLOATS (WLDSC * 512 * 4 + 256 + 512)   // 39,680 f = 158,720 B

__global__
__attribute__((amdgpu_flat_work_group_size(512, 512), amdgpu_waves_per_eu(2, 2)))
void k_rec2(const float* __restrict__ whh_f,
            const float* __restrict__ whh_b,
            float* __restrict__ ws) {
    extern __shared__ float sm[];
    float* wlds = sm;                       // [WLDSC][512][4]
    float* hbuf = sm + WLDSC * 512 * 4;     // [256]
    float* gact = hbuf + 256;               // [512]

    const float* xp = ws + XP_OFF;
    float* hx = ws + HX_OFF;
    int* flags = (int*)(ws + FLAGS_OFF);
    float* hs = ws + HS_OFF;

    const int blk = blockIdx.x;
    const int jhalf = blk >> 7;             // which h-half this block owns
    const int dir = (blk >> 6) & 1;
    const int batch = blk & 63;
    const int partner = blk ^ 128;          // same dir,batch, other half (same XCD mod 8)
    const int t = threadIdx.x;
    const int gt = t >> 7;                  // 0:i 1:f 2:g 3:o (wave-uniform)
    const int jj = t & 127;
    const int row_global = gt * 256 + jhalf * 128 + jj;
    const int col = dir * 1024 + row_global;
    const float* wrow = (dir ? whh_b : whh_f) + (size_t)row_global * 256;

    // ---- preload weights: 180 floats -> VGPR, 76 floats -> LDS
    float4 w4[WREGS];
#pragma unroll
    for (int i = 0; i < WREGS; ++i) w4[i] = *reinterpret_cast<const float4*>(wrow + i * 4);
#pragma unroll
    for (int c = 0; c < WLDSC; ++c)
        *reinterpret_cast<float4*>(&wlds[((size_t)c * 512 + t) * 4]) =
            *reinterpret_cast<const float4*>(wrow + WREGS * 4 + c * 4);

    if (t < 256) hbuf[t] = 0.f;
    float creg = 0.f;
    __syncthreads();

    const int lane = t & 63;
    float xpv_next = xp[((size_t)((dir ? 255 : 0) * 64 + batch)) * 2048 + col];

    for (int s = 0; s < 256; ++s) {
        const int tt = dir ? (255 - s) : s;
        const float xpv = xpv_next;

        // h (wave-uniform): every wave reads the full 256-float hbuf
        float4 vh = *reinterpret_cast<const float4*>(&hbuf[lane * 4]);

        float a0 = 0.f, a1 = 0.f, a2 = 0.f, a3 = 0.f;
#pragma unroll
        for (int i = 0; i < WREGS; ++i) {
            a0 += w4[i].x * RL(vh.x, i);   // h[4i+0]
            a1 += w4[i].y * RL(vh.y, i);   // h[4i+1]
            a2 += w4[i].z * RL(vh.z, i);   // h[4i+2]
            a3 += w4[i].w * RL(vh.w, i);   // h[4i+3]
        }
#pragma unroll
        for (int c = 0; c < WLDSC; ++c) {
            float4 wl = *reinterpret_cast<const float4*>(&wlds[((size_t)c * 512 + t) * 4]);
            const int l = WREGS + c;
            a0 += wl.x * RL(vh.x, l);
            a1 += wl.y * RL(vh.y, l);
            a2 += wl.z * RL(vh.z, l);
            a3 += wl.w * RL(vh.w, l);
        }
        const float acc = xpv + ((a0 + a1) + (a2 + a3));

        const float act = (gt == 2) ? tanhf(acc) : 1.f / (1.f + expf(-acc));
        gact[t] = act;
        __syncthreads();

        float hval = 0.f;
        if (t < 128) {   // waves 0,1 exactly -> uniform branch
            const float si = gact[t], sf = gact[128 + t], tg = gact[256 + t], so = gact[384 + t];
            creg = sf * creg + si * tg;
            hval = so * tanhf(creg);
            __hip_atomic_store(&hx[((size_t)(s & 1) * 256 + blk) * 128 + t], hval,
                               __ATOMIC_RELAXED, __HIP_MEMORY_SCOPE_AGENT);
            asm volatile("s_waitcnt vmcnt(0)" ::: "memory");  // own store globally visible
        }
        __syncthreads();

        if (t == 0)
            __hip_atomic_store(&flags[blk], s + 1, __ATOMIC_RELEASE, __HIP_MEMORY_SCOPE_AGENT);

        // issue next-step xp load into the exchange window
        {
            const int sn = (s < 255) ? s + 1 : 255;
            const int ttn = dir ? (255 - sn) : sn;
            xpv_next = xp[((size_t)(ttn * 64 + batch)) * 2048 + col];
        }
        if (t < 128) {
            hbuf[jhalf * 128 + t] = hval;
            hs[((size_t)(tt * 64 + batch)) * 512 + dir * 256 + jhalf * 128 + t] = hval;
        }

        if (t == 0) {
            while (__hip_atomic_load(&flags[partner], __ATOMIC_ACQUIRE,
                                     __HIP_MEMORY_SCOPE_AGENT) < s + 1) {
                __builtin_amdgcn_s_sleep(2);
            }
        }
        __syncthreads();
        if (t < 128) {
            float hp = __hip_atomic_load(&hx[((size_t)(s & 1) * 256 + partner) * 128 + t],
                                         __ATOMIC_RELAXED, __HIP_MEMORY_SCOPE_AGENT);
            hbuf[(1 - jhalf) * 128 + t] = hp;
        }
        __syncthreads();
    }
}

// ---------------------------------------------------------------------------
// Emissions: em[r][j] = dot(hstore[r][0:512], w_out[j]) + b_out[j]
__global__ __launch_bounds__(256) void k_emis(const float* __restrict__ wout,
                                              const float* __restrict__ bout,
                                              float* __restrict__ ws) {
    const float* hs = ws + HS_OFF;
    float* em = ws + EM_OFF;
    __shared__ float wl[9][512];
    __shared__ float bl[9];
    const int tid = threadIdx.x;
    for (int i = tid; i < 9 * 512; i += 256) wl[i / 512][i % 512] = wout[i];
    if (tid < 9) bl[tid] = bout[tid];
    __syncthreads();

    const int r = blockIdx.x * 256 + tid;
    const float4* hrow = reinterpret_cast<const float4*>(hs + (size_t)r * 512);
    float acc[9];
#pragma unroll
    for (int j = 0; j < 9; ++j) acc[j] = bl[j];
    for (int k4 = 0; k4 < 128; ++k4) {
        float4 h = hrow[k4];
#pragma unroll
        for (int j = 0; j < 9; ++j) {
            float4 w = *reinterpret_cast<const float4*>(&wl[j][k4 * 4]);
            acc[j] += h.x * w.x + h.y * w.y + h.z * w.z + h.w * w.w;
        }
    }
#pragma unroll
    for (int j = 0; j < 9; ++j) em[(size_t)r * 9 + j] = acc[j];
}

// ---------------------------------------------------------------------------
// Viterbi: one block per batch; strict-> first-index argmax matches jnp.
__global__ __launch_bounds__(64) void k_vit(const float* __restrict__ start,
                                            const float* __restrict__ endv,
                                            const float* __restrict__ trans,
                                            const float* __restrict__ ws_c,
                                            float* __restrict__ out) {
    const float* em = ws_c + EM_OFF;
    const int b = blockIdx.x;
    const int lane = threadIdx.x;
    __shared__ float tr[81];
    __shared__ float sc[9];
    __shared__ float ns[9];
    __shared__ int hist[256][9];

    for (int i = lane; i < 81; i += 64) tr[i] = trans[i];
    if (lane < 9) sc[lane] = start[lane] + em[(size_t)b * 9 + lane];
    __syncthreads();

    for (int t = 1; t < 256; ++t) {
        if (lane < 9) {
            float e = em[((size_t)t * 64 + b) * 9 + lane];
            float best = -1e30f; int bi = 0;
#pragma unroll
            for (int i = 0; i < 9; ++i) {
                float v = sc[i] + tr[i * 9 + lane];
                if (v > best) { best = v; bi = i; }
            }
            ns[lane] = best + e;
            hist[t][lane] = bi;
        }
        __syncthreads();
        if (lane < 9) sc[lane] = ns[lane];
        __syncthreads();
    }

    if (lane == 0) {
        float best = -1e30f; int bi = 0;
        for (int j = 0; j < 9; ++j) {
            float v = sc[j] + endv[j];
            if (v > best) { best = v; bi = j; }
        }
        out[16384 + b] = best;
        int cur = bi;
        out[(size_t)b * 256 + 255] = (float)cur;
        for (int t = 255; t >= 1; --t) {
            cur = hist[t][cur];
            out[(size_t)b * 256 + t - 1] = (float)cur;
        }
    }
}

// ---------------------------------------------------------------------------
extern "C" void kernel_launch(void* const* d_in, const int* in_sizes, int n_in,
                              void* d_out, int out_size, void* d_ws, size_t ws_size,
                              hipStream_t stream) {
    (void)in_sizes; (void)n_in; (void)out_size; (void)ws_size;
    const int*   x       = (const int*)d_in[0];
    const float* embed   = (const float*)d_in[1];
    const float* w_ih_f  = (const float*)d_in[2];
    const float* w_hh_f  = (const float*)d_in[3];
    const float* b_ih_f  = (const float*)d_in[4];
    const float* b_hh_f  = (const float*)d_in[5];
    const float* w_ih_b  = (const float*)d_in[6];
    const float* w_hh_b  = (const float*)d_in[7];
    const float* b_ih_b  = (const float*)d_in[8];
    const float* b_hh_b  = (const float*)d_in[9];
    const float* w_out   = (const float*)d_in[10];
    const float* b_out   = (const float*)d_in[11];
    const float* crf_start = (const float*)d_in[12];
    const float* crf_end   = (const float*)d_in[13];
    const float* crf_trans = (const float*)d_in[14];
    float* ws  = (float*)d_ws;
    float* out = (float*)d_out;

    const size_t rec_lds_bytes = (size_t)REC_LDS_FLOATS * 4;   // 158,720 B
    hipFuncSetAttribute(reinterpret_cast<const void*>(k_rec2),
                        hipFuncAttributeMaxDynamicSharedMemorySize,
                        (int)rec_lds_bytes);

    hipLaunchKernelGGL(k_prep, dim3(16), dim3(256), 0, stream,
                       b_ih_f, b_hh_f, b_ih_b, b_hh_b, ws);
    hipLaunchKernelGGL(k_xproj, dim3(256, 32), dim3(256), 0, stream,
                       x, embed, w_ih_f, w_ih_b, ws);
    hipLaunchKernelGGL(k_rec2, dim3(256), dim3(512), rec_lds_bytes, stream,
                       w_hh_f, w_hh_b, ws);
    hipLaunchKernelGGL(k_emis, dim3(64), dim3(256), 0, stream, w_out, b_out, ws);
    hipLaunchKernelGGL(k_vit, dim3(64), dim3(64), 0, stream,
                       crf_start, crf_end, crf_trans, ws, out);
}

// Round 5
// 1159.474 us; speedup vs baseline: 2.1064x; 2.1064x over previous
//
#include <hip/hip_runtime.h>
#include <hip/hip_bf16.h>
#include <math.h>

// Problem dims
#define VOCAB 50001
#define EDIM 256
#define HDIM 256          // per-direction hidden
#define GDIM 1024         // 4*HDIM gates
#define KTAG 9
#define NB 64             // batch
#define NT 256            // time

// workspace layout (float offsets)
static constexpr size_t XP_OFF   = 0;                            // xproj [16384][2048]
static constexpr size_t HX_OFF   = XP_OFF + (size_t)16384*2048;  // u64 hx [2][256][128]
static constexpr size_t BIAS_OFF = HX_OFF + 131072;              // [2048]
static constexpr size_t HS_OFF   = BIAS_OFF + 2048;              // hstore [16384][512]
static constexpr size_t EM_OFF   = HS_OFF + (size_t)16384*512;   // emissions [16384][9]

// readlane: h is wave-uniform -> SGPR operand for fma
#define RL(v, l) __int_as_float(__builtin_amdgcn_readlane(__float_as_int(v), (l)))

// ---------------------------------------------------------------------------
// Prep: combined bias, zero the tagged h-exchange buffer (replay-safe).
__global__ __launch_bounds__(256) void k_prep(const float* __restrict__ bif,
                                              const float* __restrict__ bhf,
                                              const float* __restrict__ bib,
                                              const float* __restrict__ bhb,
                                              float* __restrict__ ws) {
    int t = blockIdx.x * 256 + threadIdx.x;   // grid 16x256 = 4096
    float* bias = ws + BIAS_OFF;
    if (t < 2048) {
        int d = t >> 10, g = t & 1023;
        bias[t] = d ? (bib[g] + bhb[g]) : (bif[g] + bhf[g]);
    }
    unsigned long long* hx = (unsigned long long*)(ws + HX_OFF);
    for (int i = t; i < 65536; i += 4096) hx[i] = 0ull;
}

// ---------------------------------------------------------------------------
// xproj GEMM: M=16384 rows (r = t*64+b, A row = embed[x[b,t]]), N=2048
// (w_ih_f rows 0..1023 | w_ih_b rows 1024..2047), K=256. fp32, 64x64 tiles.
#define BKC 32
__global__ __launch_bounds__(256) void k_xproj(const int* __restrict__ x,
                                               const float* __restrict__ embed,
                                               const float* __restrict__ wih_f,
                                               const float* __restrict__ wih_b,
                                               float* __restrict__ ws) {
    float* xp = ws + XP_OFF;
    const float* bias = ws + BIAS_OFF;
    __shared__ float As[BKC][68];
    __shared__ float Bs[BKC][68];
    __shared__ int ids[64];
    const int bm = blockIdx.x;      // 0..255
    const int bn = blockIdx.y;      // 0..31
    const int tid = threadIdx.x;
    const int tx = tid & 15, ty = tid >> 4;

    if (tid < 64) {
        int r = bm * 64 + tid;
        int t = r >> 6, b = r & 63;
        ids[tid] = x[b * 256 + t];
    }
    __syncthreads();

    float acc[4][4];
#pragma unroll
    for (int i = 0; i < 4; ++i)
#pragma unroll
        for (int j = 0; j < 4; ++j) acc[i][j] = 0.f;

    const int lm = tid >> 2;
    const int lks = (tid & 3) * 8;

    for (int k0 = 0; k0 < 256; k0 += BKC) {
        {
            const float* src = embed + (size_t)ids[lm] * 256 + k0 + lks;
            float4 a0 = *reinterpret_cast<const float4*>(src);
            float4 a1 = *reinterpret_cast<const float4*>(src + 4);
            As[lks + 0][lm] = a0.x; As[lks + 1][lm] = a0.y;
            As[lks + 2][lm] = a0.z; As[lks + 3][lm] = a0.w;
            As[lks + 4][lm] = a1.x; As[lks + 5][lm] = a1.y;
            As[lks + 6][lm] = a1.z; As[lks + 7][lm] = a1.w;
        }
        {
            int gn = bn * 64 + lm;
            const float* wsrc = (gn < 1024) ? (wih_f + (size_t)gn * 256)
                                            : (wih_b + (size_t)(gn - 1024) * 256);
            const float* src = wsrc + k0 + lks;
            float4 b0 = *reinterpret_cast<const float4*>(src);
            float4 b1 = *reinterpret_cast<const float4*>(src + 4);
            Bs[lks + 0][lm] = b0.x; Bs[lks + 1][lm] = b0.y;
            Bs[lks + 2][lm] = b0.z; Bs[lks + 3][lm] = b0.w;
            Bs[lks + 4][lm] = b1.x; Bs[lks + 5][lm] = b1.y;
            Bs[lks + 6][lm] = b1.z; Bs[lks + 7][lm] = b1.w;
        }
        __syncthreads();
#pragma unroll
        for (int k = 0; k < BKC; ++k) {
            float4 a = *reinterpret_cast<const float4*>(&As[k][ty * 4]);
            float4 bq = *reinterpret_cast<const float4*>(&Bs[k][tx * 4]);
            acc[0][0] += a.x * bq.x; acc[0][1] += a.x * bq.y; acc[0][2] += a.x * bq.z; acc[0][3] += a.x * bq.w;
            acc[1][0] += a.y * bq.x; acc[1][1] += a.y * bq.y; acc[1][2] += a.y * bq.z; acc[1][3] += a.y * bq.w;
            acc[2][0] += a.z * bq.x; acc[2][1] += a.z * bq.y; acc[2][2] += a.z * bq.z; acc[2][3] += a.z * bq.w;
            acc[3][0] += a.w * bq.x; acc[3][1] += a.w * bq.y; acc[3][2] += a.w * bq.z; acc[3][3] += a.w * bq.w;
        }
        __syncthreads();
    }

    const int gm = bm * 64 + ty * 4;
    const int gn = bn * 64 + tx * 4;
#pragma unroll
    for (int i = 0; i < 4; ++i) {
        float4 o;
        o.x = acc[i][0] + bias[gn + 0];
        o.y = acc[i][1] + bias[gn + 1];
        o.z = acc[i][2] + bias[gn + 2];
        o.w = acc[i][3] + bias[gn + 3];
        *reinterpret_cast<float4*>(xp + (size_t)(gm + i) * 2048 + gn) = o;
    }
}

// ---------------------------------------------------------------------------
// Recurrence v3: weights CU-resident, designed for the OBSERVED 128-VGPR cap.
// 256 blocks = (jhalf, dir, batch); 1024 threads: kh = t>>9 (row k-half),
// rr = t&511 (gate-row). Per thread: 23 float4 weights in VGPR (92 regs) +
// 9 float4 in LDS. Partial sums combined via LDS. Pairwise h-half exchange
// with partner (blk^128, same XCD mod 8) via packed {tag,val} u64 atomics,
// parity double-buffered (slot reuse only after partner provably consumed).
#define WV 23
#define WL 9
#define REC_LDS_FLOATS (WL * 1024 * 4 + 256 + 512 + 512)   // 38,144 f = 152,576 B

__global__ __launch_bounds__(1024)
__attribute__((amdgpu_waves_per_eu(4, 4)))
void k_rec3(const float* __restrict__ whh_f,
            const float* __restrict__ whh_b,
            float* __restrict__ ws) {
    extern __shared__ float sm[];
    float4* wlds4 = reinterpret_cast<float4*>(sm);   // [WL][1024]
    float* hbuf = sm + WL * 1024 * 4;                // [256]
    float* gact = hbuf + 256;                        // [512]
    float* psum = gact + 512;                        // [512]

    const float* xp = ws + XP_OFF;
    unsigned long long* hx = (unsigned long long*)(ws + HX_OFF);
    float* hs = ws + HS_OFF;

    const int blk = blockIdx.x;
    const int jhalf = blk >> 7;
    const int dir = (blk >> 6) & 1;
    const int batch = blk & 63;
    const int partner = blk ^ 128;
    const int t = threadIdx.x;
    const int kh = t >> 9;                  // k-half of the row
    const int rr = t & 511;                 // row within block
    const int gt = rr >> 7;                 // gate 0:i 1:f 2:g 3:o
    const int jj = rr & 127;
    const int row_global = gt * 256 + jhalf * 128 + jj;
    const int col = dir * 1024 + row_global;
    const float* wrow = (dir ? whh_b : whh_f) + (size_t)row_global * 256 + kh * 128;

    // preload weights: 92 floats -> VGPR, 36 floats -> LDS (per thread)
    float4 w4[WV];
#pragma unroll
    for (int i = 0; i < WV; ++i) w4[i] = reinterpret_cast<const float4*>(wrow)[i];
#pragma unroll
    for (int c = 0; c < WL; ++c)
        wlds4[c * 1024 + t] = reinterpret_cast<const float4*>(wrow)[WV + c];

    if (t < 256) hbuf[t] = 0.f;
    float creg = 0.f;
    __syncthreads();

    const long xstep = dir ? -131072 : 131072;       // floats per time step
    const long hstep = dir ? -32768 : 32768;
    const float* xptr = xp + (size_t)(dir ? 255 : 0) * 131072 + (size_t)batch * 2048 + col;
    float* hsptr = hs + (size_t)(dir ? 255 : 0) * 32768 + (size_t)batch * 512
                   + dir * 256 + jhalf * 128 + t;    // only t<128 dereferences
    float xpv = (t < 512) ? *xptr : 0.f;

    for (int s = 0; s < 256; ++s) {
        // broadcast h: lanes 0..31 carry the 32 float4 of this k-half
        float4 vh = *reinterpret_cast<const float4*>(&hbuf[kh * 128 + (t & 31) * 4]);

        float a0 = 0.f, a1 = 0.f, a2 = 0.f, a3 = 0.f;
#pragma unroll
        for (int i = 0; i < WV; ++i) {
            a0 += w4[i].x * RL(vh.x, i);
            a1 += w4[i].y * RL(vh.y, i);
            a2 += w4[i].z * RL(vh.z, i);
            a3 += w4[i].w * RL(vh.w, i);
        }
#pragma unroll
        for (int c = 0; c < WL; ++c) {
            float4 wl = wlds4[c * 1024 + t];
            const int l = WV + c;
            a0 += wl.x * RL(vh.x, l);
            a1 += wl.y * RL(vh.y, l);
            a2 += wl.z * RL(vh.z, l);
            a3 += wl.w * RL(vh.w, l);
        }
        const float a = (a0 + a1) + (a2 + a3);

        if (kh) psum[rr] = a;
        __syncthreads();

        if (t < 512) {   // waves 0..7, gt wave-uniform
            const float acc = xpv + a + psum[t];
            const float act = (gt == 2) ? tanhf(acc) : 1.f / (1.f + expf(-acc));
            gact[t] = act;
        }
        __syncthreads();

        if (t < 128) {   // waves 0,1
            const float si = gact[t], sf = gact[128 + t], tg = gact[256 + t], so = gact[384 + t];
            creg = sf * creg + si * tg;
            const float hval = so * tanhf(creg);
            const unsigned long long pk =
                ((unsigned long long)(unsigned)(s + 1) << 32) | (unsigned)__float_as_uint(hval);
            __hip_atomic_store(&hx[((size_t)(s & 1) * 256 + blk) * 128 + t], pk,
                               __ATOMIC_RELAXED, __HIP_MEMORY_SCOPE_AGENT);
            hbuf[jhalf * 128 + t] = hval;
            *hsptr = hval;
            hsptr += hstep;
        }

        if (t < 512 && s < 255) { xptr += xstep; xpv = *xptr; }

        if (t < 128) {
            unsigned long long u;
            do {
                u = __hip_atomic_load(&hx[((size_t)(s & 1) * 256 + partner) * 128 + t],
                                      __ATOMIC_RELAXED, __HIP_MEMORY_SCOPE_AGENT);
            } while ((unsigned)(u >> 32) != (unsigned)(s + 1));
            hbuf[(1 - jhalf) * 128 + t] = __uint_as_float((unsigned)u);
        }
        __syncthreads();
    }
}

// ---------------------------------------------------------------------------
// Emissions: em[r][j] = dot(hstore[r][0:512], w_out[j]) + b_out[j]
__global__ __launch_bounds__(256) void k_emis(const float* __restrict__ wout,
                                              const float* __restrict__ bout,
                                              float* __restrict__ ws) {
    const float* hs = ws + HS_OFF;
    float* em = ws + EM_OFF;
    __shared__ float wl[9][512];
    __shared__ float bl[9];
    const int tid = threadIdx.x;
    for (int i = tid; i < 9 * 512; i += 256) wl[i / 512][i % 512] = wout[i];
    if (tid < 9) bl[tid] = bout[tid];
    __syncthreads();

    const int r = blockIdx.x * 256 + tid;
    const float4* hrow = reinterpret_cast<const float4*>(hs + (size_t)r * 512);
    float acc[9];
#pragma unroll
    for (int j = 0; j < 9; ++j) acc[j] = bl[j];
    for (int k4 = 0; k4 < 128; ++k4) {
        float4 h = hrow[k4];
#pragma unroll
        for (int j = 0; j < 9; ++j) {
            float4 w = *reinterpret_cast<const float4*>(&wl[j][k4 * 4]);
            acc[j] += h.x * w.x + h.y * w.y + h.z * w.z + h.w * w.w;
        }
    }
#pragma unroll
    for (int j = 0; j < 9; ++j) em[(size_t)r * 9 + j] = acc[j];
}

// ---------------------------------------------------------------------------
// Viterbi: one block per batch; strict-> first-index argmax matches jnp.
__global__ __launch_bounds__(64) void k_vit(const float* __restrict__ start,
                                            const float* __restrict__ endv,
                                            const float* __restrict__ trans,
                                            const float* __restrict__ ws_c,
                                            float* __restrict__ out) {
    const float* em = ws_c + EM_OFF;
    const int b = blockIdx.x;
    const int lane = threadIdx.x;
    __shared__ float tr[81];
    __shared__ float sc[9];
    __shared__ float ns[9];
    __shared__ int hist[256][9];

    for (int i = lane; i < 81; i += 64) tr[i] = trans[i];
    if (lane < 9) sc[lane] = start[lane] + em[(size_t)b * 9 + lane];
    __syncthreads();

    for (int t = 1; t < 256; ++t) {
        if (lane < 9) {
            float e = em[((size_t)t * 64 + b) * 9 + lane];
            float best = -1e30f; int bi = 0;
#pragma unroll
            for (int i = 0; i < 9; ++i) {
                float v = sc[i] + tr[i * 9 + lane];
                if (v > best) { best = v; bi = i; }
            }
            ns[lane] = best + e;
            hist[t][lane] = bi;
        }
        __syncthreads();
        if (lane < 9) sc[lane] = ns[lane];
        __syncthreads();
    }

    if (lane == 0) {
        float best = -1e30f; int bi = 0;
        for (int j = 0; j < 9; ++j) {
            float v = sc[j] + endv[j];
            if (v > best) { best = v; bi = j; }
        }
        out[16384 + b] = best;
        int cur = bi;
        out[(size_t)b * 256 + 255] = (float)cur;
        for (int t = 255; t >= 1; --t) {
            cur = hist[t][cur];
            out[(size_t)b * 256 + t - 1] = (float)cur;
        }
    }
}

// ---------------------------------------------------------------------------
extern "C" void kernel_launch(void* const* d_in, const int* in_sizes, int n_in,
                              void* d_out, int out_size, void* d_ws, size_t ws_size,
                              hipStream_t stream) {
    (void)in_sizes; (void)n_in; (void)out_size; (void)ws_size;
    const int*   x       = (const int*)d_in[0];
    const float* embed   = (const float*)d_in[1];
    const float* w_ih_f  = (const float*)d_in[2];
    const float* w_hh_f  = (const float*)d_in[3];
    const float* b_ih_f  = (const float*)d_in[4];
    const float* b_hh_f  = (const float*)d_in[5];
    const float* w_ih_b  = (const float*)d_in[6];
    const float* w_hh_b  = (const float*)d_in[7];
    const float* b_ih_b  = (const float*)d_in[8];
    const float* b_hh_b  = (const float*)d_in[9];
    const float* w_out   = (const float*)d_in[10];
    const float* b_out   = (const float*)d_in[11];
    const float* crf_start = (const float*)d_in[12];
    const float* crf_end   = (const float*)d_in[13];
    const float* crf_trans = (const float*)d_in[14];
    float* ws  = (float*)d_ws;
    float* out = (float*)d_out;

    const size_t rec_lds_bytes = (size_t)REC_LDS_FLOATS * 4;   // 152,576 B
    hipFuncSetAttribute(reinterpret_cast<const void*>(k_rec3),
                        hipFuncAttributeMaxDynamicSharedMemorySize,
                        (int)rec_lds_bytes);

    hipLaunchKernelGGL(k_prep, dim3(16), dim3(256), 0, stream,
                       b_ih_f, b_hh_f, b_ih_b, b_hh_b, ws);
    hipLaunchKernelGGL(k_xproj, dim3(256, 32), dim3(256), 0, stream,
                       x, embed, w_ih_f, w_ih_b, ws);
    hipLaunchKernelGGL(k_rec3, dim3(256), dim3(1024), rec_lds_bytes, stream,
                       w_hh_f, w_hh_b, ws);
    hipLaunchKernelGGL(k_emis, dim3(64), dim3(256), 0, stream, w_out, b_out, ws);
    hipLaunchKernelGGL(k_vit, dim3(64), dim3(64), 0, stream,
                       crf_start, crf_end, crf_trans, ws, out);
}

// Round 8
// 998.171 us; speedup vs baseline: 2.4467x; 1.1616x over previous
//
#include <hip/hip_runtime.h>
#include <hip/hip_bf16.h>
#include <math.h>

// Problem dims
#define VOCAB 50001
#define EDIM 256
#define HDIM 256          // per-direction hidden
#define GDIM 1024         // 4*HDIM gates
#define KTAG 9
#define NB 64             // batch
#define NT 256            // time

// workspace layout (float offsets)
static constexpr size_t XP_OFF   = 0;                            // xproj [16384][2048]
static constexpr size_t HX_OFF   = XP_OFF + (size_t)16384*2048;  // u64 hx [2][256][128]
static constexpr size_t BIAS_OFF = HX_OFF + 131072;              // [2048]
static constexpr size_t HS_OFF   = BIAS_OFF + 2048;              // hstore [16384][512]
static constexpr size_t EM_OFF   = HS_OFF + (size_t)16384*512;   // emissions [16384][9]

#define FMA4(acc, W, H) acc += (W).x*(H).x + (W).y*(H).y + (W).z*(H).z + (W).w*(H).w

// ---------------------------------------------------------------------------
// Prep: combined bias, zero the tagged h-exchange buffer (replay-safe).
__global__ __launch_bounds__(256) void k_prep(const float* __restrict__ bif,
                                              const float* __restrict__ bhf,
                                              const float* __restrict__ bib,
                                              const float* __restrict__ bhb,
                                              float* __restrict__ ws) {
    int t = blockIdx.x * 256 + threadIdx.x;   // grid 16x256 = 4096
    float* bias = ws + BIAS_OFF;
    if (t < 2048) {
        int d = t >> 10, g = t & 1023;
        bias[t] = d ? (bib[g] + bhb[g]) : (bif[g] + bhf[g]);
    }
    unsigned long long* hx = (unsigned long long*)(ws + HX_OFF);
    for (int i = t; i < 65536; i += 4096) hx[i] = 0ull;
}

// ---------------------------------------------------------------------------
// xproj GEMM: M=16384 rows (r = t*64+b, A row = embed[x[b,t]]), N=2048
// (w_ih_f rows 0..1023 | w_ih_b rows 1024..2047), K=256. fp32, 64x64 tiles.
#define BKC 32
__global__ __launch_bounds__(256) void k_xproj(const int* __restrict__ x,
                                               const float* __restrict__ embed,
                                               const float* __restrict__ wih_f,
                                               const float* __restrict__ wih_b,
                                               float* __restrict__ ws) {
    float* xp = ws + XP_OFF;
    const float* bias = ws + BIAS_OFF;
    __shared__ float As[BKC][68];
    __shared__ float Bs[BKC][68];
    __shared__ int ids[64];
    const int bm = blockIdx.x;      // 0..255
    const int bn = blockIdx.y;      // 0..31
    const int tid = threadIdx.x;
    const int tx = tid & 15, ty = tid >> 4;

    if (tid < 64) {
        int r = bm * 64 + tid;
        int t = r >> 6, b = r & 63;
        ids[tid] = x[b * 256 + t];
    }
    __syncthreads();

    float acc[4][4];
#pragma unroll
    for (int i = 0; i < 4; ++i)
#pragma unroll
        for (int j = 0; j < 4; ++j) acc[i][j] = 0.f;

    const int lm = tid >> 2;
    const int lks = (tid & 3) * 8;

    for (int k0 = 0; k0 < 256; k0 += BKC) {
        {
            const float* src = embed + (size_t)ids[lm] * 256 + k0 + lks;
            float4 a0 = *reinterpret_cast<const float4*>(src);
            float4 a1 = *reinterpret_cast<const float4*>(src + 4);
            As[lks + 0][lm] = a0.x; As[lks + 1][lm] = a0.y;
            As[lks + 2][lm] = a0.z; As[lks + 3][lm] = a0.w;
            As[lks + 4][lm] = a1.x; As[lks + 5][lm] = a1.y;
            As[lks + 6][lm] = a1.z; As[lks + 7][lm] = a1.w;
        }
        {
            int gn = bn * 64 + lm;
            const float* wsrc = (gn < 1024) ? (wih_f + (size_t)gn * 256)
                                            : (wih_b + (size_t)(gn - 1024) * 256);
            const float* src = wsrc + k0 + lks;
            float4 b0 = *reinterpret_cast<const float4*>(src);
            float4 b1 = *reinterpret_cast<const float4*>(src + 4);
            Bs[lks + 0][lm] = b0.x; Bs[lks + 1][lm] = b0.y;
            Bs[lks + 2][lm] = b0.z; Bs[lks + 3][lm] = b0.w;
            Bs[lks + 4][lm] = b1.x; Bs[lks + 5][lm] = b1.y;
            Bs[lks + 6][lm] = b1.z; Bs[lks + 7][lm] = b1.w;
        }
        __syncthreads();
#pragma unroll
        for (int k = 0; k < BKC; ++k) {
            float4 a = *reinterpret_cast<const float4*>(&As[k][ty * 4]);
            float4 bq = *reinterpret_cast<const float4*>(&Bs[k][tx * 4]);
            acc[0][0] += a.x * bq.x; acc[0][1] += a.x * bq.y; acc[0][2] += a.x * bq.z; acc[0][3] += a.x * bq.w;
            acc[1][0] += a.y * bq.x; acc[1][1] += a.y * bq.y; acc[1][2] += a.y * bq.z; acc[1][3] += a.y * bq.w;
            acc[2][0] += a.z * bq.x; acc[2][1] += a.z * bq.y; acc[2][2] += a.z * bq.z; acc[2][3] += a.z * bq.w;
            acc[3][0] += a.w * bq.x; acc[3][1] += a.w * bq.y; acc[3][2] += a.w * bq.z; acc[3][3] += a.w * bq.w;
        }
        __syncthreads();
    }

    const int gm = bm * 64 + ty * 4;
    const int gn = bn * 64 + tx * 4;
#pragma unroll
    for (int i = 0; i < 4; ++i) {
        float4 o;
        o.x = acc[i][0] + bias[gn + 0];
        o.y = acc[i][1] + bias[gn + 1];
        o.z = acc[i][2] + bias[gn + 2];
        o.w = acc[i][3] + bias[gn + 3];
        *reinterpret_cast<float4*>(xp + (size_t)(gm + i) * 2048 + gn) = o;
    }
}

// ---------------------------------------------------------------------------
// Recurrence v3b: EXACT round-5 k_rec3 skeleton (proven: 3 barriers, t<128
// spin, partner ^128, parity u64 hx) with ONE change: the h-operand comes
// from wave-uniform LDS broadcast reads (kh is uniform per wave) instead of
// v_readlane — halves the dot's VALU ops (2/elem -> 1/elem); the DS pipe
// absorbs h traffic under the FMA stream.
#define WV 23
#define WL 9
#define REC_LDS_FLOATS (WL * 1024 * 4 + 256 + 512 + 512)   // 38,144 f = 152,576 B

__global__ __launch_bounds__(1024)
__attribute__((amdgpu_waves_per_eu(4, 4)))
void k_rec3(const float* __restrict__ whh_f,
            const float* __restrict__ whh_b,
            float* __restrict__ ws) {
    extern __shared__ float sm[];
    float4* wlds4 = reinterpret_cast<float4*>(sm);   // [WL][1024]
    float* hbuf = sm + WL * 1024 * 4;                // [256]
    float* gact = hbuf + 256;                        // [512]
    float* psum = gact + 512;                        // [512]

    const float* xp = ws + XP_OFF;
    unsigned long long* hx = (unsigned long long*)(ws + HX_OFF);
    float* hs = ws + HS_OFF;

    const int blk = blockIdx.x;
    const int jhalf = blk >> 7;
    const int dir = (blk >> 6) & 1;
    const int batch = blk & 63;
    const int partner = blk ^ 128;
    const int t = threadIdx.x;
    const int kh = t >> 9;                  // k-half of the row (wave-uniform)
    const int rr = t & 511;                 // row within block
    const int gt = rr >> 7;                 // gate 0:i 1:f 2:g 3:o
    const int jj = rr & 127;
    const int row_global = gt * 256 + jhalf * 128 + jj;
    const int col = dir * 1024 + row_global;
    const float* wrow = (dir ? whh_b : whh_f) + (size_t)row_global * 256 + kh * 128;

    // preload weights: 92 floats -> VGPR, 36 floats -> LDS (per thread)
    float4 w4[WV];
#pragma unroll
    for (int i = 0; i < WV; ++i) w4[i] = reinterpret_cast<const float4*>(wrow)[i];
#pragma unroll
    for (int c = 0; c < WL; ++c)
        wlds4[c * 1024 + t] = reinterpret_cast<const float4*>(wrow)[WV + c];

    if (t < 256) hbuf[t] = 0.f;
    float creg = 0.f;
    __syncthreads();

    const long xstep = dir ? -131072 : 131072;       // floats per time step
    const long hstep = dir ? -32768 : 32768;
    const float* xptr = xp + (size_t)(dir ? 255 : 0) * 131072 + (size_t)batch * 2048 + col;
    float* hsptr = hs + (size_t)(dir ? 255 : 0) * 32768 + (size_t)batch * 512
                   + dir * 256 + jhalf * 128 + t;    // only t<128 dereferences
    float xpv = (t < 512) ? *xptr : 0.f;

    for (int s = 0; s < 256; ++s) {
        // h operand: wave-uniform broadcast reads from LDS (kh uniform/wave)
        const float* hk = hbuf + kh * 128;

        float a0 = 0.f, a1 = 0.f, a2 = 0.f, a3 = 0.f;
#pragma unroll
        for (int q = 0; q < WV; q += 4) {
            float4 h4;
            h4 = *reinterpret_cast<const float4*>(hk + (q + 0) * 4);
            FMA4(a0, w4[q + 0], h4);
            if (q + 1 < WV) { h4 = *reinterpret_cast<const float4*>(hk + (q + 1) * 4); FMA4(a1, w4[q + 1], h4); }
            if (q + 2 < WV) { h4 = *reinterpret_cast<const float4*>(hk + (q + 2) * 4); FMA4(a2, w4[q + 2], h4); }
            if (q + 3 < WV) { h4 = *reinterpret_cast<const float4*>(hk + (q + 3) * 4); FMA4(a3, w4[q + 3], h4); }
        }
#pragma unroll
        for (int c = 0; c < WL; ++c) {
            float4 h4 = *reinterpret_cast<const float4*>(hk + (WV + c) * 4);
            float4 wl = wlds4[c * 1024 + t];
            if ((c & 3) == 0) FMA4(a0, wl, h4);
            else if ((c & 3) == 1) FMA4(a1, wl, h4);
            else if ((c & 3) == 2) FMA4(a2, wl, h4);
            else FMA4(a3, wl, h4);
        }
        const float a = (a0 + a1) + (a2 + a3);

        if (kh) psum[rr] = a;
        __syncthreads();

        if (t < 512) {   // waves 0..7, gt wave-uniform
            const float acc = xpv + a + psum[t];
            const float act = (gt == 2) ? tanhf(acc) : 1.f / (1.f + expf(-acc));
            gact[t] = act;
        }
        __syncthreads();

        if (t < 128) {   // waves 0,1
            const float si = gact[t], sf = gact[128 + t], tg = gact[256 + t], so = gact[384 + t];
            creg = sf * creg + si * tg;
            const float hval = so * tanhf(creg);
            const unsigned long long pk =
                ((unsigned long long)(unsigned)(s + 1) << 32) | (unsigned)__float_as_uint(hval);
            __hip_atomic_store(&hx[((size_t)(s & 1) * 256 + blk) * 128 + t], pk,
                               __ATOMIC_RELAXED, __HIP_MEMORY_SCOPE_AGENT);
            hbuf[jhalf * 128 + t] = hval;
            *hsptr = hval;
            hsptr += hstep;
        }

        if (t < 512 && s < 255) { xptr += xstep; xpv = *xptr; }

        if (t < 128) {
            unsigned long long u;
            do {
                u = __hip_atomic_load(&hx[((size_t)(s & 1) * 256 + partner) * 128 + t],
                                      __ATOMIC_RELAXED, __HIP_MEMORY_SCOPE_AGENT);
            } while ((unsigned)(u >> 32) != (unsigned)(s + 1));
            hbuf[(1 - jhalf) * 128 + t] = __uint_as_float((unsigned)u);
        }
        __syncthreads();
    }
}

// ---------------------------------------------------------------------------
// Emissions: em[r][j] = dot(hstore[r][0:512], w_out[j]) + b_out[j]
__global__ __launch_bounds__(256) void k_emis(const float* __restrict__ wout,
                                              const float* __restrict__ bout,
                                              float* __restrict__ ws) {
    const float* hs = ws + HS_OFF;
    float* em = ws + EM_OFF;
    __shared__ float wl[9][512];
    __shared__ float bl[9];
    const int tid = threadIdx.x;
    for (int i = tid; i < 9 * 512; i += 256) wl[i / 512][i % 512] = wout[i];
    if (tid < 9) bl[tid] = bout[tid];
    __syncthreads();

    const int r = blockIdx.x * 256 + tid;
    const float4* hrow = reinterpret_cast<const float4*>(hs + (size_t)r * 512);
    float acc[9];
#pragma unroll
    for (int j = 0; j < 9; ++j) acc[j] = bl[j];
    for (int k4 = 0; k4 < 128; ++k4) {
        float4 h = hrow[k4];
#pragma unroll
        for (int j = 0; j < 9; ++j) {
            float4 w = *reinterpret_cast<const float4*>(&wl[j][k4 * 4]);
            acc[j] += h.x * w.x + h.y * w.y + h.z * w.z + h.w * w.w;
        }
    }
#pragma unroll
    for (int j = 0; j < 9; ++j) em[(size_t)r * 9 + j] = acc[j];
}

// ---------------------------------------------------------------------------
// Viterbi: one block per batch; strict-> first-index argmax matches jnp.
__global__ __launch_bounds__(64) void k_vit(const float* __restrict__ start,
                                            const float* __restrict__ endv,
                                            const float* __restrict__ trans,
                                            const float* __restrict__ ws_c,
                                            float* __restrict__ out) {
    const float* em = ws_c + EM_OFF;
    const int b = blockIdx.x;
    const int lane = threadIdx.x;
    __shared__ float tr[81];
    __shared__ float sc[9];
    __shared__ float ns[9];
    __shared__ int hist[256][9];

    for (int i = lane; i < 81; i += 64) tr[i] = trans[i];
    if (lane < 9) sc[lane] = start[lane] + em[(size_t)b * 9 + lane];
    __syncthreads();

    for (int t = 1; t < 256; ++t) {
        if (lane < 9) {
            float e = em[((size_t)t * 64 + b) * 9 + lane];
            float best = -1e30f; int bi = 0;
#pragma unroll
            for (int i = 0; i < 9; ++i) {
                float v = sc[i] + tr[i * 9 + lane];
                if (v > best) { best = v; bi = i; }
            }
            ns[lane] = best + e;
            hist[t][lane] = bi;
        }
        __syncthreads();
        if (lane < 9) sc[lane] = ns[lane];
        __syncthreads();
    }

    if (lane == 0) {
        float best = -1e30f; int bi = 0;
        for (int j = 0; j < 9; ++j) {
            float v = sc[j] + endv[j];
            if (v > best) { best = v; bi = j; }
        }
        out[16384 + b] = best;
        int cur = bi;
        out[(size_t)b * 256 + 255] = (float)cur;
        for (int t = 255; t >= 1; --t) {
            cur = hist[t][cur];
            out[(size_t)b * 256 + t - 1] = (float)cur;
        }
    }
}

// ---------------------------------------------------------------------------
extern "C" void kernel_launch(void* const* d_in, const int* in_sizes, int n_in,
                              void* d_out, int out_size, void* d_ws, size_t ws_size,
                              hipStream_t stream) {
    (void)in_sizes; (void)n_in; (void)out_size; (void)ws_size;
    const int*   x       = (const int*)d_in[0];
    const float* embed   = (const float*)d_in[1];
    const float* w_ih_f  = (const float*)d_in[2];
    const float* w_hh_f  = (const float*)d_in[3];
    const float* b_ih_f  = (const float*)d_in[4];
    const float* b_hh_f  = (const float*)d_in[5];
    const float* w_ih_b  = (const float*)d_in[6];
    const float* w_hh_b  = (const float*)d_in[7];
    const float* b_ih_b  = (const float*)d_in[8];
    const float* b_hh_b  = (const float*)d_in[9];
    const float* w_out   = (const float*)d_in[10];
    const float* b_out   = (const float*)d_in[11];
    const float* crf_start = (const float*)d_in[12];
    const float* crf_end   = (const float*)d_in[13];
    const float* crf_trans = (const float*)d_in[14];
    float* ws  = (float*)d_ws;
    float* out = (float*)d_out;

    const size_t rec_lds_bytes = (size_t)REC_LDS_FLOATS * 4;   // 152,576 B
    hipFuncSetAttribute(reinterpret_cast<const void*>(k_rec3),
                        hipFuncAttributeMaxDynamicSharedMemorySize,
                        (int)rec_lds_bytes);

    hipLaunchKernelGGL(k_prep, dim3(16), dim3(256), 0, stream,
                       b_ih_f, b_hh_f, b_ih_b, b_hh_b, ws);
    hipLaunchKernelGGL(k_xproj, dim3(256, 32), dim3(256), 0, stream,
                       x, embed, w_ih_f, w_ih_b, ws);
    hipLaunchKernelGGL(k_rec3, dim3(256), dim3(1024), rec_lds_bytes, stream,
                       w_hh_f, w_hh_b, ws);
    hipLaunchKernelGGL(k_emis, dim3(64), dim3(256), 0, stream, w_out, b_out, ws);
    hipLaunchKernelGGL(k_vit, dim3(64), dim3(64), 0, stream,
                       crf_start, crf_end, crf_trans, ws, out);
}